// Round 10
// baseline (39.772 us; speedup 1.0000x reference)
//
#include <hip/hip_runtime.h>

#define H 10
#define NIT 15
#define NPAIR 9   // 9 float2 pairs = 18 rays per lane (ray-parity split)

typedef float v2f __attribute__((ext_vector_type(2)));

__device__ __forceinline__ float rcp_fast(float x) { return __builtin_amdgcn_rcpf(x); }
__device__ __forceinline__ float rsq_fast(float x) { return __builtin_amdgcn_rsqf(x); }

// DPP quad_perm cross-lane exchange: VALU pipe, no LDS, no lgkmcnt.
// XOR1 = quad_perm[1,0,3,2] = 0xB1 ; XOR2 = quad_perm[2,3,0,1] = 0x4E.
template <int CTRL>
__device__ __forceinline__ float dpp_qp(float x) {
    int i = __builtin_bit_cast(int, x);
    int r = __builtin_amdgcn_update_dpp(i, i, CTRL, 0xF, 0xF, true);
    return __builtin_bit_cast(float, r);
}
#define DPP_XOR1 0xB1
#define DPP_XOR2 0x4E

// Forced VOP3P packed-f32 (CDNA2+). Neutral if clang already packs v2f ops;
// big win if it scalarizes.
__device__ __forceinline__ v2f pk_add(v2f a, v2f b) {
    v2f r;
    asm("v_pk_add_f32 %0, %1, %2" : "=v"(r) : "v"(a), "v"(b));
    return r;
}
__device__ __forceinline__ v2f pk_mul(v2f a, v2f b) {
    v2f r;
    asm("v_pk_mul_f32 %0, %1, %2" : "=v"(r) : "v"(a), "v"(b));
    return r;
}
__device__ __forceinline__ v2f pk_fma(v2f a, v2f b, v2f c) {
    v2f r;
    asm("v_pk_fma_f32 %0, %1, %2, %3" : "=v"(r) : "v"(a), "v"(b), "v"(c));
    return r;
}

__device__ __forceinline__ float fast_atan2f(float y, float x) {
    float ax = fabsf(x), ay = fabsf(y);
    float mx = fmaxf(ax, ay), mn = fminf(ax, ay);
    float z = mn * rcp_fast(mx);
    float z2 = z * z;
    // minimax atan(z), z in [0,1], max err ~2e-6 rad
    float p = fmaf(z2, -0.01172120f, 0.05265332f);
    p = fmaf(z2, p, -0.11643287f);
    p = fmaf(z2, p, 0.19354346f);
    p = fmaf(z2, p, -0.33262347f);
    p = fmaf(z2, p, 0.99997726f);
    p = p * z;
    p = (ay > ax) ? (1.5707964f - p) : p;
    p = (x < 0.0f) ? (3.1415927f - p) : p;
    return copysignf(p, y);
}

// LDS-demotion traps (journal):
//  (1) __launch_bounds__(256, 1) -> promote-alloca demotes unrolled arrays
//      to LDS (round 7: 20KB LDS, 307K conflict cycles). Keep plain (256).
//  (2) `cond ? arr[i] : arr[j]` with RUNTIME cond is a select of ADDRESSES ->
//      dynamic GEP -> SROA fails -> array lands in LDS (rounds 7-8). Always
//      load both elements into scalars, then select on VALUES.
__global__ __launch_bounds__(256) void mpc_kernel(
    const float* __restrict__ init_state, // (B,3)
    const float* __restrict__ scan,       // (B,36)
    const float* __restrict__ target,     // (B,2)
    const float* __restrict__ wdp, const float* __restrict__ wop,
    const float* __restrict__ wap, const float* __restrict__ wvp,
    const float* __restrict__ wwp,
    float* __restrict__ out, int B)
{
    constexpr float DTc  = 0.1f;
    constexpr float MAXV = 0.22f;
    constexpr float MAXW = 2.8f;
    constexpr float LRB  = 0.2f / 16384.0f;   // LR_INNER / B
    constexpr float VK   = 0.5f * MAXV * DTc; // v*DT = (a0+1)*VK
    constexpr float WKD  = MAXW * DTc;        // w*DT = a1*WKD

    const int tid  = threadIdx.x;
    const int g    = blockIdx.x * 256 + tid;
    const int b    = g >> 2;
    const int sub  = tid & 3;
    const int rpar = sub & 1;          // ray-parity handled by this lane
    const int tpar = (sub >> 1) & 1;   // t-parity handled by this lane
    if (b >= B) return;

    // per-lane obstacle slice, stored NEGATED so ddx = xp + nox is a plain pk_add.
    v2f noxp[NPAIR], noyp[NPAIR];
    #pragma unroll
    for (int j = 0; j < NPAIR; ++j) {
        int rA = rpar + 4 * j;
        int rB = rA + 2;
        float angA = (float)rA * 0.17951958020513104f;  // 2*pi/35 (linspace endpoint incl.)
        float angB = (float)rB * 0.17951958020513104f;
        float sA, cA, sB, cB;
        __sincosf(angA, &sA, &cA);
        __sincosf(angB, &sB, &cB);
        float dA = scan[b * 36 + rA];
        float dB = scan[b * 36 + rB];
        noxp[j] = (v2f){-dA * cA, -dB * cB};
        noyp[j] = (v2f){-dA * sA, -dB * sB};
    }

    const float x0   = init_state[b * 3 + 0];
    const float y0   = init_state[b * 3 + 1];
    const float yaw0 = init_state[b * 3 + 2];
    const float tx   = target[b * 2 + 0];
    const float ty   = target[b * 2 + 1];
    const float wd2 = wdp[b] * 20.0f;   // 2 * (wd*10)
    const float wo  = wop[b] * 100.0f;
    const float wa2 = wap[b] * 10.0f;   // 2 * (wa*5)

    // folded phase-C constants (algebraically exact rearrangement)
    const float Kv   = -LRB * 0.5f * MAXV * DTc;
    const float Kw   = -LRB * MAXW * DTc;
    const float wvK2 = wvp[b] * 200.0f;  // wv2/DT * v = wvK2 * vd
    const float wwK  = wwp[b] * 5.6f;    // ww2/DT * w = wwK * a1

    float c0, s0;
    __sincosf(yaw0, &s0, &c0);          // yaw0 constant across GD iters

    float a[H][2];
    #pragma unroll
    for (int t = 0; t < H; ++t) { a[t][0] = 0.0f; a[t][1] = 0.0f; }

    for (int it = 0; it < NIT; ++it) {
        // ---------- Phase A: forward rollout (DT folded into controls) ----------
        float cv[H], sv[H], px[H], py[H], vd[H];
        float x = x0, y = y0, c = c0, s = s0;
        #pragma unroll
        for (int t = 0; t < H; ++t) {
            cv[t] = c; sv[t] = s;                   // heading BEFORE step t
            float vdt = fmaf(a[t][0], VK, VK);      // v*DT
            float zd  = a[t][1] * WKD;              // w*DT
            vd[t] = vdt;
            x = fmaf(vdt, c, x);
            y = fmaf(vdt, s, y);
            float z2 = zd * zd;
            float cz = fmaf(z2, -0.5f, 1.0f);       // cos(zd) to 2nd order
            float t1 = s * zd;
            float t2 = c * zd;
            float cn = fmaf(c, cz, -t1);
            float sn = fmaf(s, cz,  t2);
            c = cn; s = sn;
            px[t] = x; py[t] = y;                   // position AFTER step t
        }

        // ---------- Phase B: 5 issued steps cover 10 t's (t-parity split) ----------
        float pgxE[5], pgxO[5], pgyE[5], pgyO[5], pcaE[5], pcaO[5];
        #pragma unroll
        for (int k = 0; k < 5; ++k) {
            // my t = 2k + tpar. Load both candidates at constant indices, select on VALUES.
            const float xpE = px[2 * k],     xpO = px[2 * k + 1];
            const float ypE = py[2 * k],     ypO = py[2 * k + 1];
            const float cAE = cv[2 * k + 1], sAE = sv[2 * k + 1];
            const float cAO = (k == 4) ? c : cv[(2 * k + 2) % H];
            const float sAO = (k == 4) ? s : sv[(2 * k + 2) % H];
            const float xp = tpar ? xpO : xpE;
            const float yp = tpar ? ypO : ypE;
            const float cA = tpar ? cAO : cAE;
            const float sA = tpar ? sAO : sAE;

            float dx = tx - xp, dy = ty - yp;
            // aerr = wrap(atan2(dy,dx) - yaw') == atan2(dy*c - dx*s, dx*c + dy*s)
            float nn = fmaf(dy, cA, -dx * sA);
            float dd = fmaf(dx, cA,  dy * sA);
            float aerr = fast_atan2f(nn, dd);
            float ca = wa2 * aerr;
            float r2 = fmaf(dx, dx, dy * dy);
            float cr = ca * rcp_fast(r2);
            float gx = fmaf(-wd2, dx,  cr * dy);
            float gy = fmaf(-wd2, dy, -cr * dx);

            // 18-ray EXACT argmin, packed-f32 distance core, first candidate peeled
            v2f xp2 = (v2f){xp, xp}, yp2 = (v2f){yp, yp};
            v2f ddx0 = pk_add(xp2, noxp[0]);
            v2f ddy0 = pk_add(yp2, noyp[0]);
            v2f d2v0 = pk_fma(ddy0, ddy0, pk_mul(ddx0, ddx0));
            float bestd2 = d2v0.x, bdx = ddx0.x, bdy = ddy0.x;
            {
                bool c1b = d2v0.y < bestd2;
                bestd2 = fminf(d2v0.y, bestd2);
                bdx = c1b ? ddx0.y : bdx;
                bdy = c1b ? ddy0.y : bdy;
            }
            #pragma unroll
            for (int j = 1; j < NPAIR; ++j) {
                v2f ddx = pk_add(xp2, noxp[j]);
                v2f ddy = pk_add(yp2, noyp[j]);
                v2f d2v = pk_fma(ddy, ddy, pk_mul(ddx, ddx));
                bool c0b = d2v.x < bestd2;
                bestd2 = fminf(d2v.x, bestd2);
                bdx = c0b ? ddx.x : bdx;
                bdy = c0b ? ddy.x : bdy;
                bool c1b = d2v.y < bestd2;
                bestd2 = fminf(d2v.y, bestd2);
                bdx = c1b ? ddx.y : bdx;
                bdy = c1b ? ddy.y : bdy;
            }
            {
                float od2 = dpp_qp<DPP_XOR1>(bestd2);
                float odx = dpp_qp<DPP_XOR1>(bdx);
                float ody = dpp_qp<DPP_XOR1>(bdy);
                bool cb = od2 < bestd2;
                bestd2 = fminf(od2, bestd2);
                bdx = cb ? odx : bdx;
                bdy = cb ? ody : bdy;
            }
            float rin  = rsq_fast(bestd2);      // 1/mind
            float mind = bestd2 * rin;
            float m    = fmaxf(0.4f - mind, 0.0f);
            float sg   = -4.0f * wo * m * m * m * rin;   // 0 when no collision
            float pgx = fmaf(sg, bdx, gx);
            float pgy = fmaf(sg, bdy, gy);

            // t-parity exchange via DPP xor2 (VALU), C stays exchange-free
            float ogx = dpp_qp<DPP_XOR2>(pgx);
            float ogy = dpp_qp<DPP_XOR2>(pgy);
            float oca = dpp_qp<DPP_XOR2>(ca);
            pgxE[k] = tpar ? ogx : pgx;  pgxO[k] = tpar ? pgx : ogx;
            pgyE[k] = tpar ? ogy : pgy;  pgyO[k] = tpar ? pgy : ogy;
            pcaE[k] = tpar ? oca : ca;   pcaO[k] = tpar ? ca  : oca;
        }

        // ---------- Phase C: thin serial adjoint sweep (folded: 12 ops/t) ----------
        float Gx = 0.0f, Gy = 0.0f, Gyaw = 0.0f;
        #pragma unroll
        for (int t = H - 1; t >= 0; --t) {
            const int k = t >> 1;
            float pgx = (t & 1) ? pgxO[k] : pgxE[k];   // (t&1) folds at compile time
            float pgy = (t & 1) ? pgyO[k] : pgyE[k];
            float pca = (t & 1) ? pcaO[k] : pcaE[k];
            float gx   = Gx + pgx;
            float gy   = Gy + pgy;
            float gyaw = Gyaw - pca;
            const float cy = cv[t], sy = sv[t], vdt = vd[t];

            float gvp = fmaf(gx, cy, gy * sy);       // gv/DT core
            gvp = fmaf(wvK2, vdt, gvp);              // + wv-regularizer
            a[t][0] = fmaf(gvp, Kv, a[t][0]);

            float a1old = a[t][1];
            float gwp = fmaf(wwK, a1old, gyaw);      // gw/DT
            a[t][1] = fmaf(gwp, Kw, a1old);

            float m1 = gy * cy;
            float m2 = fmaf(-gx, sy, m1);
            Gyaw = fmaf(vdt, m2, gyaw);
            Gx = gx;
            Gy = gy;
        }
    }

    if (sub == 0) {
        float v = (tanhf(a[0][0]) + 1.0f) * 0.5f * MAXV;   // final output: libm-precise
        float w = tanhf(a[0][1]) * MAXW;
        out[b * 2 + 0] = v;
        out[b * 2 + 1] = w;
    }
}

extern "C" void kernel_launch(void* const* d_in, const int* in_sizes, int n_in,
                              void* d_out, int out_size, void* d_ws, size_t ws_size,
                              hipStream_t stream) {
    const float* init_state = (const float*)d_in[0];
    const float* scan       = (const float*)d_in[1];
    const float* target     = (const float*)d_in[2];
    const float* wd         = (const float*)d_in[3];
    const float* wo         = (const float*)d_in[4];
    const float* wa         = (const float*)d_in[5];
    const float* wv         = (const float*)d_in[6];
    const float* ww         = (const float*)d_in[7];
    int B = in_sizes[0] / 3;
    int threads = B * 4;
    int blocks = (threads + 255) / 256;
    mpc_kernel<<<blocks, 256, 0, stream>>>(init_state, scan, target, wd, wo, wa, wv, ww,
                                           (float*)d_out, B);
}

// Round 11
// 36.909 us; speedup vs baseline: 1.0776x; 1.0776x over previous
//
#include <hip/hip_runtime.h>

#define H 10
#define NIT 15
#define NPAIR 9   // 9 float2 pairs = 18 rays per lane (ray-parity split)

typedef float v2f __attribute__((ext_vector_type(2)));

__device__ __forceinline__ float rcp_fast(float x) { return __builtin_amdgcn_rcpf(x); }
__device__ __forceinline__ float rsq_fast(float x) { return __builtin_amdgcn_rsqf(x); }

// DPP quad_perm cross-lane exchange: VALU pipe, no LDS, no lgkmcnt.
// XOR1 = quad_perm[1,0,3,2] = 0xB1 ; XOR2 = quad_perm[2,3,0,1] = 0x4E.
template <int CTRL>
__device__ __forceinline__ float dpp_qp(float x) {
    int i = __builtin_bit_cast(int, x);
    int r = __builtin_amdgcn_update_dpp(i, i, CTRL, 0xF, 0xF, true);
    return __builtin_bit_cast(float, r);
}
#define DPP_XOR1 0xB1
#define DPP_XOR2 0x4E

__device__ __forceinline__ float fast_atan2f(float y, float x) {
    float ax = fabsf(x), ay = fabsf(y);
    float mx = fmaxf(ax, ay), mn = fminf(ax, ay);
    float z = mn * rcp_fast(mx);
    float z2 = z * z;
    // minimax atan(z), z in [0,1], max err ~2e-6 rad
    float p = fmaf(z2, -0.01172120f, 0.05265332f);
    p = fmaf(z2, p, -0.11643287f);
    p = fmaf(z2, p, 0.19354346f);
    p = fmaf(z2, p, -0.33262347f);
    p = fmaf(z2, p, 0.99997726f);
    p = p * z;
    p = (ay > ax) ? (1.5707964f - p) : p;
    p = (x < 0.0f) ? (3.1415927f - p) : p;
    return copysignf(p, y);
}

// LDS-demotion traps (journal):
//  (1) `cond ? arr[i] : arr[j]` with RUNTIME cond is a select of ADDRESSES ->
//      dynamic GEP -> SROA fails -> alloca survives -> promote-alloca parks it
//      in LDS (rounds 7-8: 20KB LDS, 307K conflict cycles). Always load both
//      elements into scalars, then select on VALUES.
//  (2) With all-constant indexing, SROA eliminates the allocas early, so
//      __launch_bounds__(256, 1) is safe AND lifts the VGPR cap to 512 --
//      at 1 wave/SIMD (grid == machine size) spare registers are free and the
//      scheduler can overlap phase B's five independent dependency chains.
__global__ __launch_bounds__(256, 1) void mpc_kernel(
    const float* __restrict__ init_state, // (B,3)
    const float* __restrict__ scan,       // (B,36)
    const float* __restrict__ target,     // (B,2)
    const float* __restrict__ wdp, const float* __restrict__ wop,
    const float* __restrict__ wap, const float* __restrict__ wvp,
    const float* __restrict__ wwp,
    float* __restrict__ out, int B)
{
    constexpr float DTc  = 0.1f;
    constexpr float MAXV = 0.22f;
    constexpr float MAXW = 2.8f;
    constexpr float LRB  = 0.2f / 16384.0f;   // LR_INNER / B
    constexpr float VK   = 0.5f * MAXV * DTc; // v*DT = (a0+1)*VK
    constexpr float WKD  = MAXW * DTc;        // w*DT = a1*WKD

    const int tid  = threadIdx.x;
    const int g    = blockIdx.x * 256 + tid;
    const int b    = g >> 2;
    const int sub  = tid & 3;
    const int rpar = sub & 1;          // ray-parity handled by this lane
    const int tpar = (sub >> 1) & 1;   // t-parity handled by this lane
    if (b >= B) return;

    // per-lane obstacle slice: 18 rays, pairs (rA = rpar+4j, rB = rA+2)
    v2f oxp[NPAIR], oyp[NPAIR];
    #pragma unroll
    for (int j = 0; j < NPAIR; ++j) {
        int rA = rpar + 4 * j;
        int rB = rA + 2;
        float angA = (float)rA * 0.17951958020513104f;  // 2*pi/35 (linspace endpoint incl.)
        float angB = (float)rB * 0.17951958020513104f;
        float sA, cA, sB, cB;
        __sincosf(angA, &sA, &cA);
        __sincosf(angB, &sB, &cB);
        float dA = scan[b * 36 + rA];
        float dB = scan[b * 36 + rB];
        oxp[j] = (v2f){dA * cA, dB * cB};
        oyp[j] = (v2f){dA * sA, dB * sB};
    }

    const float x0   = init_state[b * 3 + 0];
    const float y0   = init_state[b * 3 + 1];
    const float yaw0 = init_state[b * 3 + 2];
    const float tx   = target[b * 2 + 0];
    const float ty   = target[b * 2 + 1];
    const float wd2 = wdp[b] * 20.0f;   // 2 * (wd*10)
    const float wo  = wop[b] * 100.0f;
    const float wa2 = wap[b] * 10.0f;   // 2 * (wa*5)

    // folded phase-C constants (algebraically exact rearrangement)
    const float Kv   = -LRB * 0.5f * MAXV * DTc;
    const float Kw   = -LRB * MAXW * DTc;
    const float wvK2 = wvp[b] * 200.0f;  // wv2/DT * v = wvK2 * vd
    const float wwK  = wwp[b] * 5.6f;    // ww2/DT * w = wwK * a1

    float c0, s0;
    __sincosf(yaw0, &s0, &c0);          // yaw0 constant across GD iters

    float a[H][2];
    #pragma unroll
    for (int t = 0; t < H; ++t) { a[t][0] = 0.0f; a[t][1] = 0.0f; }

    for (int it = 0; it < NIT; ++it) {
        // ---------- Phase A: forward rollout (DT folded into controls) ----------
        float cv[H], sv[H], px[H], py[H], vd[H];
        float x = x0, y = y0, c = c0, s = s0;
        #pragma unroll
        for (int t = 0; t < H; ++t) {
            cv[t] = c; sv[t] = s;                   // heading BEFORE step t
            float vdt = fmaf(a[t][0], VK, VK);      // v*DT
            float zd  = a[t][1] * WKD;              // w*DT
            vd[t] = vdt;
            x = fmaf(vdt, c, x);
            y = fmaf(vdt, s, y);
            float z2 = zd * zd;
            float cz = fmaf(z2, -0.5f, 1.0f);       // cos(zd) to 2nd order
            float t1 = s * zd;
            float t2 = c * zd;
            float cn = fmaf(c, cz, -t1);
            float sn = fmaf(s, cz,  t2);
            c = cn; s = sn;
            px[t] = x; py[t] = y;                   // position AFTER step t
        }

        // ---------- Phase B: 5 issued steps cover 10 t's (t-parity split) ----------
        float pgxE[5], pgxO[5], pgyE[5], pgyO[5], pcaE[5], pcaO[5];
        #pragma unroll
        for (int k = 0; k < 5; ++k) {
            // my t = 2k + tpar. Load both candidates at constant indices, select on VALUES.
            const float xpE = px[2 * k],     xpO = px[2 * k + 1];
            const float ypE = py[2 * k],     ypO = py[2 * k + 1];
            const float cAE = cv[2 * k + 1], sAE = sv[2 * k + 1];
            const float cAO = (k == 4) ? c : cv[(2 * k + 2) % H];
            const float sAO = (k == 4) ? s : sv[(2 * k + 2) % H];
            const float xp = tpar ? xpO : xpE;
            const float yp = tpar ? ypO : ypE;
            const float cA = tpar ? cAO : cAE;
            const float sA = tpar ? sAO : sAE;

            float dx = tx - xp, dy = ty - yp;
            // aerr = wrap(atan2(dy,dx) - yaw') == atan2(dy*c - dx*s, dx*c + dy*s)
            float nn = fmaf(dy, cA, -dx * sA);
            float dd = fmaf(dx, cA,  dy * sA);
            float aerr = fast_atan2f(nn, dd);
            float ca = wa2 * aerr;
            float r2 = fmaf(dx, dx, dy * dy);
            float cr = ca * rcp_fast(r2);
            float gx = fmaf(-wd2, dx,  cr * dy);
            float gy = fmaf(-wd2, dy, -cr * dx);

            // 18-ray EXACT argmin (rolling min + select), first candidate peeled
            v2f xp2 = (v2f){xp, xp}, yp2 = (v2f){yp, yp};
            v2f ddx0 = xp2 - oxp[0];
            v2f ddy0 = yp2 - oyp[0];
            v2f d2v0 = ddx0 * ddx0 + ddy0 * ddy0;
            float bestd2 = d2v0.x, bdx = ddx0.x, bdy = ddy0.x;
            {
                bool c1b = d2v0.y < bestd2;
                bestd2 = fminf(d2v0.y, bestd2);
                bdx = c1b ? ddx0.y : bdx;
                bdy = c1b ? ddy0.y : bdy;
            }
            #pragma unroll
            for (int j = 1; j < NPAIR; ++j) {
                v2f ddx = xp2 - oxp[j];
                v2f ddy = yp2 - oyp[j];
                v2f d2v = ddx * ddx + ddy * ddy;
                bool c0b = d2v.x < bestd2;
                bestd2 = fminf(d2v.x, bestd2);
                bdx = c0b ? ddx.x : bdx;
                bdy = c0b ? ddy.x : bdy;
                bool c1b = d2v.y < bestd2;
                bestd2 = fminf(d2v.y, bestd2);
                bdx = c1b ? ddx.y : bdx;
                bdy = c1b ? ddy.y : bdy;
            }
            {
                float od2 = dpp_qp<DPP_XOR1>(bestd2);
                float odx = dpp_qp<DPP_XOR1>(bdx);
                float ody = dpp_qp<DPP_XOR1>(bdy);
                bool cb = od2 < bestd2;
                bestd2 = fminf(od2, bestd2);
                bdx = cb ? odx : bdx;
                bdy = cb ? ody : bdy;
            }
            float rin  = rsq_fast(bestd2);      // 1/mind
            float mind = bestd2 * rin;
            float m    = fmaxf(0.4f - mind, 0.0f);
            float sg   = -4.0f * wo * m * m * m * rin;   // 0 when no collision
            float pgx = fmaf(sg, bdx, gx);
            float pgy = fmaf(sg, bdy, gy);

            // t-parity exchange via DPP xor2 (VALU), C stays exchange-free
            float ogx = dpp_qp<DPP_XOR2>(pgx);
            float ogy = dpp_qp<DPP_XOR2>(pgy);
            float oca = dpp_qp<DPP_XOR2>(ca);
            pgxE[k] = tpar ? ogx : pgx;  pgxO[k] = tpar ? pgx : ogx;
            pgyE[k] = tpar ? ogy : pgy;  pgyO[k] = tpar ? pgy : ogy;
            pcaE[k] = tpar ? oca : ca;   pcaO[k] = tpar ? ca  : oca;
        }

        // ---------- Phase C: thin serial adjoint sweep (folded consts; (t&1)
        //            ternaries fold at compile time) ----------
        float Gx = 0.0f, Gy = 0.0f, Gyaw = 0.0f;
        #pragma unroll
        for (int t = H - 1; t >= 0; --t) {
            const int k = t >> 1;
            float pgx = (t & 1) ? pgxO[k] : pgxE[k];
            float pgy = (t & 1) ? pgyO[k] : pgyE[k];
            float pca = (t & 1) ? pcaO[k] : pcaE[k];
            float gx   = Gx + pgx;
            float gy   = Gy + pgy;
            float gyaw = Gyaw - pca;
            const float cy = cv[t], sy = sv[t], vdt = vd[t];

            float gvp = fmaf(gx, cy, gy * sy);       // gv/DT core
            gvp = fmaf(wvK2, vdt, gvp);              // + wv-regularizer
            a[t][0] = fmaf(gvp, Kv, a[t][0]);

            float a1old = a[t][1];
            float gwp = fmaf(wwK, a1old, gyaw);      // gw/DT
            a[t][1] = fmaf(gwp, Kw, a1old);

            float m1 = gy * cy;
            float m2 = fmaf(-gx, sy, m1);
            Gyaw = fmaf(vdt, m2, gyaw);
            Gx = gx;
            Gy = gy;
        }
    }

    if (sub == 0) {
        float v = (tanhf(a[0][0]) + 1.0f) * 0.5f * MAXV;   // final output: libm-precise
        float w = tanhf(a[0][1]) * MAXW;
        out[b * 2 + 0] = v;
        out[b * 2 + 1] = w;
    }
}

extern "C" void kernel_launch(void* const* d_in, const int* in_sizes, int n_in,
                              void* d_out, int out_size, void* d_ws, size_t ws_size,
                              hipStream_t stream) {
    const float* init_state = (const float*)d_in[0];
    const float* scan       = (const float*)d_in[1];
    const float* target     = (const float*)d_in[2];
    const float* wd         = (const float*)d_in[3];
    const float* wo         = (const float*)d_in[4];
    const float* wa         = (const float*)d_in[5];
    const float* wv         = (const float*)d_in[6];
    const float* ww         = (const float*)d_in[7];
    int B = in_sizes[0] / 3;
    int threads = B * 4;
    int blocks = (threads + 255) / 256;
    mpc_kernel<<<blocks, 256, 0, stream>>>(init_state, scan, target, wd, wo, wa, wv, ww,
                                           (float*)d_out, B);
}